// Round 2
// baseline (116.559 us; speedup 1.0000x reference)
//
#include <hip/hip_runtime.h>

#define CC 256
#define EE 128
#define BB 8
#define NN 3136
#define NN4 784      // NN / 4 (float4 per row)
#define T4 8         // float4 per i-tile (32 spatial positions)
#define NTILES 98    // NN4 / T4

__device__ __forceinline__ float waveReduceSum(float v) {
    #pragma unroll
    for (int off = 32; off > 0; off >>= 1) v += __shfl_down(v, off, 64);
    return v;
}

// kA: weight prep FIRST (latency-bound blocks start early, overlap BW sweep),
//     then the xbar HBM sweep.
//   blk 0        : A[c] = Wcat[:E]·Wq[:,c] + Wcat[E:]·Wk[:,c];  cst
//   blk 1..256   : r = blk-1:  MgT[k][r] = sum_e Wexp[r,e]*Wv[e,k]  (transposed!)
//                  hg[r] = Wexp[r,:]·bv
//   blk 257..2304: xbar[row] = mean_i x[row, i]
__global__ void __launch_bounds__(256) kA(
        const float* __restrict__ x,
        const float* __restrict__ Wq, const float* __restrict__ bq,
        const float* __restrict__ Wk, const float* __restrict__ bk,
        const float* __restrict__ Wv, const float* __restrict__ bv,
        const float* __restrict__ Wcat, const float* __restrict__ Wexp,
        float* __restrict__ xbar, float* __restrict__ MgT, float* __restrict__ hg,
        float* __restrict__ Ag, float* __restrict__ cst) {
    const int blk = blockIdx.x;
    const int tid = threadIdx.x;
    if (blk == 0) {
        float a = 0.f;
        #pragma unroll 8
        for (int e = 0; e < EE; e++)
            a += Wcat[e] * Wq[e * CC + tid] + Wcat[EE + e] * Wk[e * CC + tid];
        Ag[tid] = a;
        if (tid < 64) {
            float cp = Wcat[tid] * bq[tid] + Wcat[tid + 64] * bq[tid + 64]
                     + Wcat[EE + tid] * bk[tid] + Wcat[EE + tid + 64] * bk[tid + 64];
            cp = waveReduceSum(cp);
            if (tid == 0) cst[0] = cp;
        }
    } else if (blk <= CC) {
        const int r = blk - 1;
        __shared__ float we_s[EE];
        if (tid < EE) we_s[tid] = Wexp[r * EE + tid];
        __syncthreads();
        float m = 0.f;
        #pragma unroll 8
        for (int e = 0; e < EE; e++) m += we_s[e] * Wv[e * CC + tid];
        MgT[tid * CC + r] = m;               // transposed store: MgT[k][r]
        if (tid < 64) {
            float hp = we_s[tid] * bv[tid] + we_s[tid + 64] * bv[tid + 64];
            hp = waveReduceSum(hp);
            if (tid == 0) hg[r] = hp;
        }
    } else {
        const int row = blk - (CC + 1);      // 0..2047
        const float4* xr = (const float4*)(x + (size_t)row * NN);
        float acc = 0.f;
        for (int i = tid; i < NN4; i += 256) {
            float4 v = xr[i];
            acc += (v.x + v.y) + (v.z + v.w);
        }
        acc = waveReduceSum(acc);
        __shared__ float red[4];
        int wid = tid >> 6, lane = tid & 63;
        if (lane == 0) red[wid] = acc;
        __syncthreads();
        if (tid == 0) xbar[row] = (red[0] + red[1] + red[2] + red[3]) * (1.0f / NN);
    }
}

// kB: fused gexp + s + out. block = (b, tile of 8 float4 = 32 spatial positions).
//   g[c=tid] = hg[c] + sum_k MgT[k][c] * xbar[b,k]   (L2-resident M, coalesced)
//   s[i]     = relu(sum_c A[c]*x[b,c,i] + cst)
//   out      = x + s*g + bexp
// x-tile loads are issued BEFORE the g-dot so HBM latency hides under the
// 256-iteration L2-bound dot.
__global__ void __launch_bounds__(256, 4) kB(
        const float* __restrict__ x, const float* __restrict__ xbar,
        const float* __restrict__ MgT, const float* __restrict__ hg,
        const float* __restrict__ Ag, const float* __restrict__ cst,
        const float* __restrict__ bexp, float* __restrict__ out) {
    const int b    = blockIdx.x / NTILES;
    const int tile = blockIdx.x - b * NTILES;
    const int tid  = threadIdx.x;
    const int i4l = tid & 7, cgr = tid >> 3;   // 8 i-slots x 32 c-groups (8 ch each)

    __shared__ float A_s[CC];
    __shared__ float xb_s[CC];
    __shared__ float g_s[CC];
    __shared__ float be_s[CC];
    __shared__ float4 part[32][8];
    __shared__ float4 s_s[8];

    A_s[tid]  = Ag[tid];
    xb_s[tid] = xbar[b * CC + tid];
    be_s[tid] = bexp[tid];
    __syncthreads();

    const float4* x4 = (const float4*)x + (size_t)b * CC * NN4 + tile * T4;
    float4*       o4 = (float4*)out     + (size_t)b * CC * NN4 + tile * T4;

    // issue the 8 HBM tile loads first
    float4 xc[8];
    #pragma unroll
    for (int j = 0; j < 8; j++)
        xc[j] = x4[(size_t)(cgr * 8 + j) * NN4 + i4l];

    // gexp dot over L2-resident transposed M (overlaps the loads above)
    float g = hg[tid];
    #pragma unroll 8
    for (int k = 0; k < CC; k++)
        g = fmaf(MgT[k * CC + tid], xb_s[k], g);
    g_s[tid] = g;

    // s partials from the registered x-tile
    float4 acc4 = make_float4(0.f, 0.f, 0.f, 0.f);
    #pragma unroll
    for (int j = 0; j < 8; j++) {
        const float a = A_s[cgr * 8 + j];
        const float4 v = xc[j];
        acc4.x = fmaf(a, v.x, acc4.x);
        acc4.y = fmaf(a, v.y, acc4.y);
        acc4.z = fmaf(a, v.z, acc4.z);
        acc4.w = fmaf(a, v.w, acc4.w);
    }
    part[cgr][i4l] = acc4;
    __syncthreads();

    if (tid < 8) {
        float4 sum = part[0][tid];
        #pragma unroll
        for (int g2 = 1; g2 < 32; g2++) {
            float4 p = part[g2][tid];
            sum.x += p.x; sum.y += p.y; sum.z += p.z; sum.w += p.w;
        }
        const float cv = cst[0];
        float4 s;
        s.x = fmaxf(sum.x + cv, 0.f);
        s.y = fmaxf(sum.y + cv, 0.f);
        s.z = fmaxf(sum.z + cv, 0.f);
        s.w = fmaxf(sum.w + cv, 0.f);
        s_s[tid] = s;
    }
    __syncthreads();

    const float4 sv = s_s[i4l];
    #pragma unroll
    for (int j = 0; j < 8; j++) {
        const int c = cgr * 8 + j;
        const float gg = g_s[c];
        const float be = be_s[c];
        const float4 xv = xc[j];
        float4 o;
        o.x = fmaf(sv.x, gg, xv.x) + be;
        o.y = fmaf(sv.y, gg, xv.y) + be;
        o.z = fmaf(sv.z, gg, xv.z) + be;
        o.w = fmaf(sv.w, gg, xv.w) + be;
        o4[(size_t)c * NN4 + i4l] = o;
    }
}

extern "C" void kernel_launch(void* const* d_in, const int* in_sizes, int n_in,
                              void* d_out, int out_size, void* d_ws, size_t ws_size,
                              hipStream_t stream) {
    const float* x    = (const float*)d_in[0];
    const float* Wq   = (const float*)d_in[1];
    const float* bq   = (const float*)d_in[2];
    const float* Wk   = (const float*)d_in[3];
    const float* bk   = (const float*)d_in[4];
    const float* Wv   = (const float*)d_in[5];
    const float* bv   = (const float*)d_in[6];
    const float* Wcat = (const float*)d_in[7];
    const float* Wexp = (const float*)d_in[8];
    const float* bexp = (const float*)d_in[9];
    float* out = (float*)d_out;

    float* ws   = (float*)d_ws;
    float* xbar = ws;                 // 2048
    float* Ag   = ws + 2048;          // 256
    float* cst  = ws + 2304;          // 1 (+pad)
    float* hg   = ws + 2320;          // 256
    float* MgT  = ws + 2576;          // 65536 (transposed M: MgT[k][c])

    kA<<<1 + CC + BB * CC, 256, 0, stream>>>(x, Wq, bq, Wk, bk, Wv, bv, Wcat, Wexp,
                                             xbar, MgT, hg, Ag, cst);
    kB<<<BB * NTILES, 256, 0, stream>>>(x, xbar, MgT, hg, Ag, cst, bexp, out);
}